// Round 1
// baseline (514.832 us; speedup 1.0000x reference)
//
#include <hip/hip_runtime.h>
#include <hip/hip_bf16.h>

// HopfieldLayer: out = softmax(x @ Wl^T * beta) @ Wc^T
//   x  [16384, 768] f32, Wl [4096, 768] f32, Wc [768, 4096] f32 -> out [16384, 768] f32
// Strategy: bf16 MFMA, two gemm_bt (m97-style) kernels with fused exp / normalize
// epilogues. Scores are in [-0.15, 0.15] so softmax needs no max subtraction.

#define NTOK   16384
#define DIM    768
#define NPROT  4096
#define BETA_F 0.03608439182428583f

typedef __bf16 bf16_t;
typedef __bf16 bf16x8 __attribute__((ext_vector_type(8)));
typedef float  floatx4 __attribute__((ext_vector_type(4)));

// ---------------------------------------------------------------- async 16B copy
__device__ __forceinline__ void async_copy16(const bf16_t* g, void* l) {
  __builtin_amdgcn_global_load_lds(
      (__attribute__((address_space(1))) const void*)g,
      (__attribute__((address_space(3))) void*)l, 16, 0, 0);
}

// ---------------------------------------------------------------- f32 -> bf16
__global__ __launch_bounds__(256) void cvt_bf16(const float* __restrict__ in,
                                                bf16_t* __restrict__ out, int n8) {
  int i = blockIdx.x * 256 + threadIdx.x;
  if (i >= n8) return;
  const float4* in4 = (const float4*)in;
  float4 a = in4[2 * i], b = in4[2 * i + 1];
  bf16x8 o;
  o[0] = (bf16_t)a.x; o[1] = (bf16_t)a.y; o[2] = (bf16_t)a.z; o[3] = (bf16_t)a.w;
  o[4] = (bf16_t)b.x; o[5] = (bf16_t)b.y; o[6] = (bf16_t)b.z; o[7] = (bf16_t)b.w;
  ((bf16x8*)out)[i] = o;
}

// ---------------------------------------------------------------- gemm C = A * B^T
// A: M x K row-major bf16, B: N x K row-major bf16. 128x128 block tile, BK=64,
// 256 threads = 4 waves in 2x2, each wave 64x64 (4x4 tiles of 16x16x32 MFMA).
// LDS holds tiles in MFMA-fragment order: frag(mtg,kt) is a 1KB block, lane l's
// 16B at +l*16 holds A[mtg*16 + (l&15)][kt*32 + (l>>4)*8 .. +7]. The global-side
// addresses are permuted to match, so ds_read_b128 is perfectly conflict-free
// and global_load_lds's uniform-base+lane*16 constraint is honored.
// EPI 0: C = exp(beta*acc) as bf16 (P matrix) + atomic rowsum.  EPI 1: C(f32) = acc/rowsum.
template <int EPI>
__global__ __launch_bounds__(256, 3)
void gemm_bt(const bf16_t* __restrict__ A, const bf16_t* __restrict__ B,
             void* __restrict__ Cv, float* __restrict__ rowsum,
             const int K, const int N) {
  __shared__ alignas(16) char lds[32768];
  bf16x8* Afr = (bf16x8*)lds;
  bf16x8* Bfr = (bf16x8*)(lds + 16384);

  const int tid = threadIdx.x;
  const int l   = tid & 63;
  const int w   = tid >> 6;
  const int wr  = w >> 1;        // wave row (0..1)
  const int wc  = w & 1;         // wave col (0..1)
  const int lr  = l & 15;        // row within 16x16 fragment
  const int lk  = (l >> 4) << 3; // k offset within fragment (0,8,16,24)
  const int m0  = blockIdx.y * 128;
  const int n0  = blockIdx.x * 128;

  // staging bases: thread (w,l), chunk j -> fragment 4j+w, lane slot l
  int abase[4], bbase[4];
#pragma unroll
  for (int j = 0; j < 4; ++j) {
    const int frag = 4 * j + w;
    const int mtg = frag >> 1, kt = frag & 1;
    abase[j] = (m0 + mtg * 16 + lr) * K + kt * 32 + lk;
    bbase[j] = (n0 + mtg * 16 + lr) * K + kt * 32 + lk;
  }

  const floatx4 z = {0.f, 0.f, 0.f, 0.f};
  floatx4 acc[4][4];
#pragma unroll
  for (int mt = 0; mt < 4; ++mt)
#pragma unroll
    for (int nt = 0; nt < 4; ++nt) acc[mt][nt] = z;

  for (int k0 = 0; k0 < K; k0 += 64) {
#pragma unroll
    for (int j = 0; j < 4; ++j) {
      const int frag = 4 * j + w;
      async_copy16(A + abase[j] + k0, Afr + frag * 64);
      async_copy16(B + bbase[j] + k0, Bfr + frag * 64);
    }
    __syncthreads();  // compiler emits s_waitcnt vmcnt(0) before s_barrier
#pragma unroll
    for (int kt = 0; kt < 2; ++kt) {
      bf16x8 af[4], bg[4];
#pragma unroll
      for (int mt = 0; mt < 4; ++mt) af[mt] = Afr[((wr * 4 + mt) * 2 + kt) * 64 + l];
#pragma unroll
      for (int nt = 0; nt < 4; ++nt) bg[nt] = Bfr[((wc * 4 + nt) * 2 + kt) * 64 + l];
#pragma unroll
      for (int mt = 0; mt < 4; ++mt)
#pragma unroll
        for (int nt = 0; nt < 4; ++nt)
          acc[mt][nt] = __builtin_amdgcn_mfma_f32_16x16x32_bf16(af[mt], bg[nt],
                                                                acc[mt][nt], 0, 0, 0);
    }
    __syncthreads();
  }

  // C/D layout (verified m89): col = lane&15, row = (lane>>4)*4 + i
  const int rowb = m0 + wr * 64;
  const int colb = n0 + wc * 64;
  if (EPI == 0) {
    bf16_t* P = (bf16_t*)Cv;
#pragma unroll
    for (int mt = 0; mt < 4; ++mt) {
      float rsum[4] = {0.f, 0.f, 0.f, 0.f};
#pragma unroll
      for (int nt = 0; nt < 4; ++nt) {
#pragma unroll
        for (int i = 0; i < 4; ++i) {
          const float e = __expf(acc[mt][nt][i] * BETA_F);
          const int row = rowb + mt * 16 + (l >> 4) * 4 + i;
          const int col = colb + nt * 16 + lr;
          P[row * N + col] = (bf16_t)e;
          rsum[i] += e;
        }
      }
#pragma unroll
      for (int i = 0; i < 4; ++i) {  // reduce across the 16 col-lanes
        float s = rsum[i];
        s += __shfl_xor(s, 1);
        s += __shfl_xor(s, 2);
        s += __shfl_xor(s, 4);
        s += __shfl_xor(s, 8);
        if (lr == 0)
          atomicAdd(&rowsum[rowb + mt * 16 + (l >> 4) * 4 + i], s);
      }
    }
  } else {
    float* O = (float*)Cv;
#pragma unroll
    for (int mt = 0; mt < 4; ++mt) {
#pragma unroll
      for (int i = 0; i < 4; ++i) {
        const int row = rowb + mt * 16 + (l >> 4) * 4 + i;
        const float inv = 1.0f / rowsum[row];
#pragma unroll
        for (int nt = 0; nt < 4; ++nt)
          O[row * N + colb + nt * 16 + lr] = acc[mt][nt][i] * inv;
      }
    }
  }
}

// ---------------------------------------------------------------- fallback (no ws)
// Correct-but-slow fused fp32 path, used only if ws_size is too small.
__global__ __launch_bounds__(256) void hopfield_fallback(
    const float* __restrict__ x, const float* __restrict__ wl,
    const float* __restrict__ wc, float* __restrict__ out) {
  __shared__ float  xs[8 * 768];
  __shared__ bf16_t ps[8 * 4096];
  __shared__ float  rs[8];
  const int tid = threadIdx.x;
  const int r0  = blockIdx.x * 8;
  if (tid < 8) rs[tid] = 0.f;
  for (int i = tid; i < 8 * 768; i += 256)
    xs[i] = x[(r0 + (i / 768)) * 768 + (i % 768)];
  __syncthreads();

  float lsum[8] = {0, 0, 0, 0, 0, 0, 0, 0};
  for (int p = tid; p < 4096; p += 256) {
    float s[8] = {0, 0, 0, 0, 0, 0, 0, 0};
    for (int d = 0; d < 768; ++d) {
      const float wv = wl[p * 768 + d];
#pragma unroll
      for (int r = 0; r < 8; ++r) s[r] += xs[r * 768 + d] * wv;
    }
#pragma unroll
    for (int r = 0; r < 8; ++r) {
      const float e = __expf(s[r] * BETA_F);
      ps[r * 4096 + p] = (bf16_t)e;
      lsum[r] += e;
    }
  }
#pragma unroll
  for (int r = 0; r < 8; ++r) atomicAdd(&rs[r], lsum[r]);
  __syncthreads();

  for (int d = tid; d < 768; d += 256) {
    float o[8] = {0, 0, 0, 0, 0, 0, 0, 0};
    for (int p = 0; p < 4096; ++p) {
      const float wv = wc[d * 4096 + p];
#pragma unroll
      for (int r = 0; r < 8; ++r) o[r] += (float)ps[r * 4096 + p] * wv;
    }
#pragma unroll
    for (int r = 0; r < 8; ++r) out[(r0 + r) * 768 + d] = o[r] / rs[r];
  }
}

// ---------------------------------------------------------------- launcher
extern "C" void kernel_launch(void* const* d_in, const int* in_sizes, int n_in,
                              void* d_out, int out_size, void* d_ws, size_t ws_size,
                              hipStream_t stream) {
  (void)in_sizes; (void)n_in; (void)out_size;
  const float* x  = (const float*)d_in[0];
  const float* wl = (const float*)d_in[1];
  const float* wc = (const float*)d_in[2];
  float* out = (float*)d_out;

  const size_t xb_e = (size_t)NTOK * DIM;    // 12.58M
  const size_t wl_e = (size_t)NPROT * DIM;   // 3.15M
  const size_t wc_e = (size_t)DIM * NPROT;   // 3.15M
  const size_t P_e  = (size_t)NTOK * NPROT;  // 67.1M
  const size_t need = (xb_e + wl_e + wc_e + P_e) * 2 + (size_t)NTOK * 4;

  if (ws_size >= need) {
    char* ws = (char*)d_ws;
    bf16_t* xb  = (bf16_t*)ws;  ws += xb_e * 2;
    bf16_t* wlb = (bf16_t*)ws;  ws += wl_e * 2;
    bf16_t* wcb = (bf16_t*)ws;  ws += wc_e * 2;
    bf16_t* P   = (bf16_t*)ws;  ws += P_e * 2;
    float* rowsum = (float*)ws;

    hipMemsetAsync(rowsum, 0, NTOK * sizeof(float), stream);
    cvt_bf16<<<(int)(xb_e / 8 / 256), 256, 0, stream>>>(x, xb, (int)(xb_e / 8));
    cvt_bf16<<<(int)(wl_e / 8 / 256), 256, 0, stream>>>(wl, wlb, (int)(wl_e / 8));
    cvt_bf16<<<(int)(wc_e / 8 / 256), 256, 0, stream>>>(wc, wcb, (int)(wc_e / 8));
    // scores+exp+rowsum: M=16384, N=4096, K=768
    gemm_bt<0><<<dim3(NPROT / 128, NTOK / 128), 256, 0, stream>>>(
        xb, wlb, (void*)P, rowsum, DIM, NPROT);
    // content+normalize: M=16384, N=768, K=4096
    gemm_bt<1><<<dim3(DIM / 128, NTOK / 128), 256, 0, stream>>>(
        P, wcb, (void*)out, rowsum, NPROT, DIM);
  } else {
    hopfield_fallback<<<NTOK / 8, 256, 0, stream>>>(x, wl, wc, out);
  }
}

// Round 2
// 508.820 us; speedup vs baseline: 1.0118x; 1.0118x over previous
//
#include <hip/hip_runtime.h>
#include <hip/hip_bf16.h>

// HopfieldLayer: out = softmax(x @ Wl^T * beta) @ Wc^T
//   x  [16384, 768] f32, Wl [4096, 768] f32, Wc [768, 4096] f32 -> out [16384, 768] f32
// bf16 MFMA, two gemm_bt (m97-style) kernels.
// R2: GEMM1 epilogue LDS-repack -> coalesced dwordx4 P stores + fused rowsum;
//     __launch_bounds__(256,4) (124 regs fit 128); single fused cvt kernel.

#define NTOK   16384
#define DIM    768
#define NPROT  4096
#define BETA_F 0.03608439182428583f

typedef __bf16 bf16_t;
typedef __bf16 bf16x8 __attribute__((ext_vector_type(8)));
typedef float  floatx4 __attribute__((ext_vector_type(4)));

// ---------------------------------------------------------------- async 16B copy
__device__ __forceinline__ void async_copy16(const bf16_t* g, void* l) {
  __builtin_amdgcn_global_load_lds(
      (__attribute__((address_space(1))) const void*)g,
      (__attribute__((address_space(3))) void*)l, 16, 0, 0);
}

// ---------------------------------------------------------------- f32 -> bf16 (all 3 inputs, one launch)
__global__ __launch_bounds__(256) void cvt_all(
    const float* __restrict__ x, const float* __restrict__ wl,
    const float* __restrict__ wc, bf16_t* __restrict__ xb,
    bf16_t* __restrict__ wlb, bf16_t* __restrict__ wcb,
    int nx8, int nw8, int nc8) {
  int i = blockIdx.x * 256 + threadIdx.x;
  const float* in; bf16_t* out; int k;
  if (i < nx8)            { in = x;  out = xb;  k = i; }
  else if (i < nx8 + nw8) { in = wl; out = wlb; k = i - nx8; }
  else if (i < nx8 + nw8 + nc8) { in = wc; out = wcb; k = i - nx8 - nw8; }
  else return;
  const float4* in4 = (const float4*)in;
  float4 a = in4[2 * k], b = in4[2 * k + 1];
  bf16x8 o;
  o[0] = (bf16_t)a.x; o[1] = (bf16_t)a.y; o[2] = (bf16_t)a.z; o[3] = (bf16_t)a.w;
  o[4] = (bf16_t)b.x; o[5] = (bf16_t)b.y; o[6] = (bf16_t)b.z; o[7] = (bf16_t)b.w;
  ((bf16x8*)out)[k] = o;
}

// ---------------------------------------------------------------- gemm C = A * B^T
// A: M x K row-major bf16, B: N x K row-major bf16. 128x128 tile, BK=64, 4 waves
// 2x2, each 64x64. LDS in MFMA-fragment order (global addresses permuted to
// match) -> global_load_lds width 16 + conflict-free ds_read_b128.
// EPI 0: P = exp(beta*acc) bf16 via LDS repack + coalesced stores + rowsum atomics.
// EPI 1: O(f32) = acc / rowsum[row].
template <int EPI>
__global__ __launch_bounds__(256, 4)
void gemm_bt(const bf16_t* __restrict__ A, const bf16_t* __restrict__ B,
             void* __restrict__ Cv, float* __restrict__ rowsum,
             const int K, const int N) {
  __shared__ alignas(16) char lds[EPI == 0 ? 34816 : 32768];  // repack needs 128*136*2
  bf16x8* Afr = (bf16x8*)lds;
  bf16x8* Bfr = (bf16x8*)(lds + 16384);

  const int tid = threadIdx.x;
  const int l   = tid & 63;
  const int w   = tid >> 6;
  const int wr  = w >> 1;        // wave row (0..1)
  const int wc  = w & 1;         // wave col (0..1)
  const int lr  = l & 15;        // row within 16x16 fragment
  const int lk  = (l >> 4) << 3; // k offset within fragment (0,8,16,24)
  const int m0  = blockIdx.y * 128;
  const int n0  = blockIdx.x * 128;

  int abase[4], bbase[4];
#pragma unroll
  for (int j = 0; j < 4; ++j) {
    const int frag = 4 * j + w;
    const int mtg = frag >> 1, kt = frag & 1;
    abase[j] = (m0 + mtg * 16 + lr) * K + kt * 32 + lk;
    bbase[j] = (n0 + mtg * 16 + lr) * K + kt * 32 + lk;
  }

  const floatx4 z = {0.f, 0.f, 0.f, 0.f};
  floatx4 acc[4][4];
#pragma unroll
  for (int mt = 0; mt < 4; ++mt)
#pragma unroll
    for (int nt = 0; nt < 4; ++nt) acc[mt][nt] = z;

  for (int k0 = 0; k0 < K; k0 += 64) {
#pragma unroll
    for (int j = 0; j < 4; ++j) {
      const int frag = 4 * j + w;
      async_copy16(A + abase[j] + k0, Afr + frag * 64);
      async_copy16(B + bbase[j] + k0, Bfr + frag * 64);
    }
    __syncthreads();
#pragma unroll
    for (int kt = 0; kt < 2; ++kt) {
      bf16x8 af[4], bg[4];
#pragma unroll
      for (int mt = 0; mt < 4; ++mt) af[mt] = Afr[((wr * 4 + mt) * 2 + kt) * 64 + l];
#pragma unroll
      for (int nt = 0; nt < 4; ++nt) bg[nt] = Bfr[((wc * 4 + nt) * 2 + kt) * 64 + l];
#pragma unroll
      for (int mt = 0; mt < 4; ++mt)
#pragma unroll
        for (int nt = 0; nt < 4; ++nt)
          acc[mt][nt] = __builtin_amdgcn_mfma_f32_16x16x32_bf16(af[mt], bg[nt],
                                                                acc[mt][nt], 0, 0, 0);
    }
    __syncthreads();
  }

  // C/D layout (verified m89): col = lane&15, row = (lane>>4)*4 + i
  if (EPI == 0) {
    // phase 1: exp -> bf16 into LDS tile [128 x 136] (stride 136 -> <=2-way write conflicts)
    bf16_t* Pl = (bf16_t*)lds;
#pragma unroll
    for (int mt = 0; mt < 4; ++mt)
#pragma unroll
      for (int nt = 0; nt < 4; ++nt)
#pragma unroll
        for (int i = 0; i < 4; ++i) {
          const float e  = __expf(acc[mt][nt][i] * BETA_F);
          const int  rl  = wr * 64 + mt * 16 + (l >> 4) * 4 + i;
          const int  cl  = wc * 64 + nt * 16 + lr;
          Pl[rl * 136 + cl] = (bf16_t)e;
        }
    __syncthreads();
    // phase 2: 2 lanes/row, 8x b128 read -> 8x dwordx4 store, rowsum on the fly
    const int r = tid >> 1, h = tid & 1;
    bf16_t* Pg = (bf16_t*)Cv + (size_t)(m0 + r) * N + n0;
    float s = 0.f;
#pragma unroll
    for (int j = 0; j < 8; ++j) {
      bf16x8 v = *(const bf16x8*)(Pl + r * 136 + (2 * j + h) * 8);
      ((bf16x8*)Pg)[2 * j + h] = v;
#pragma unroll
      for (int e2 = 0; e2 < 8; ++e2) s += (float)v[e2];
    }
    s += __shfl_xor(s, 1);
    if (h == 0) atomicAdd(&rowsum[m0 + r], s);
  } else {
    float* O = (float*)Cv;
    const int rowb = m0 + wr * 64;
    const int colb = n0 + wc * 64;
#pragma unroll
    for (int mt = 0; mt < 4; ++mt) {
#pragma unroll
      for (int i = 0; i < 4; ++i) {
        const int row = rowb + mt * 16 + (l >> 4) * 4 + i;
        const float inv = 1.0f / rowsum[row];
#pragma unroll
        for (int nt = 0; nt < 4; ++nt)
          O[row * N + colb + nt * 16 + lr] = acc[mt][nt][i] * inv;
      }
    }
  }
}

// ---------------------------------------------------------------- fallback (no ws)
__global__ __launch_bounds__(256) void hopfield_fallback(
    const float* __restrict__ x, const float* __restrict__ wl,
    const float* __restrict__ wc, float* __restrict__ out) {
  __shared__ float  xs[8 * 768];
  __shared__ bf16_t ps[8 * 4096];
  __shared__ float  rs[8];
  const int tid = threadIdx.x;
  const int r0  = blockIdx.x * 8;
  if (tid < 8) rs[tid] = 0.f;
  for (int i = tid; i < 8 * 768; i += 256)
    xs[i] = x[(r0 + (i / 768)) * 768 + (i % 768)];
  __syncthreads();

  float lsum[8] = {0, 0, 0, 0, 0, 0, 0, 0};
  for (int p = tid; p < 4096; p += 256) {
    float s[8] = {0, 0, 0, 0, 0, 0, 0, 0};
    for (int d = 0; d < 768; ++d) {
      const float wv = wl[p * 768 + d];
#pragma unroll
      for (int r = 0; r < 8; ++r) s[r] += xs[r * 768 + d] * wv;
    }
#pragma unroll
    for (int r = 0; r < 8; ++r) {
      const float e = __expf(s[r] * BETA_F);
      ps[r * 4096 + p] = (bf16_t)e;
      lsum[r] += e;
    }
  }
#pragma unroll
  for (int r = 0; r < 8; ++r) atomicAdd(&rs[r], lsum[r]);
  __syncthreads();

  for (int d = tid; d < 768; d += 256) {
    float o[8] = {0, 0, 0, 0, 0, 0, 0, 0};
    for (int p = 0; p < 4096; ++p) {
      const float wv = wc[d * 4096 + p];
#pragma unroll
      for (int r = 0; r < 8; ++r) o[r] += (float)ps[r * 4096 + p] * wv;
    }
#pragma unroll
    for (int r = 0; r < 8; ++r) out[(r0 + r) * 768 + d] = o[r] / rs[r];
  }
}

// ---------------------------------------------------------------- launcher
extern "C" void kernel_launch(void* const* d_in, const int* in_sizes, int n_in,
                              void* d_out, int out_size, void* d_ws, size_t ws_size,
                              hipStream_t stream) {
  (void)in_sizes; (void)n_in; (void)out_size;
  const float* x  = (const float*)d_in[0];
  const float* wl = (const float*)d_in[1];
  const float* wc = (const float*)d_in[2];
  float* out = (float*)d_out;

  const size_t xb_e = (size_t)NTOK * DIM;    // 12.58M
  const size_t wl_e = (size_t)NPROT * DIM;   // 3.15M
  const size_t wc_e = (size_t)DIM * NPROT;   // 3.15M
  const size_t P_e  = (size_t)NTOK * NPROT;  // 67.1M
  const size_t need = (xb_e + wl_e + wc_e + P_e) * 2 + (size_t)NTOK * 4;

  if (ws_size >= need) {
    char* ws = (char*)d_ws;
    bf16_t* xb  = (bf16_t*)ws;  ws += xb_e * 2;
    bf16_t* wlb = (bf16_t*)ws;  ws += wl_e * 2;
    bf16_t* wcb = (bf16_t*)ws;  ws += wc_e * 2;
    bf16_t* P   = (bf16_t*)ws;  ws += P_e * 2;
    float* rowsum = (float*)ws;

    hipMemsetAsync(rowsum, 0, NTOK * sizeof(float), stream);
    const int nx8 = (int)(xb_e / 8), nw8 = (int)(wl_e / 8), nc8 = (int)(wc_e / 8);
    cvt_all<<<(nx8 + nw8 + nc8 + 255) / 256, 256, 0, stream>>>(
        x, wl, wc, xb, wlb, wcb, nx8, nw8, nc8);
    // scores+exp+rowsum: M=16384, N=4096, K=768
    gemm_bt<0><<<dim3(NPROT / 128, NTOK / 128), 256, 0, stream>>>(
        xb, wlb, (void*)P, rowsum, DIM, NPROT);
    // content+normalize: M=16384, N=768, K=4096
    gemm_bt<1><<<dim3(DIM / 128, NTOK / 128), 256, 0, stream>>>(
        P, wcb, (void*)out, rowsum, NPROT, DIM);
  } else {
    hopfield_fallback<<<NTOK / 8, 256, 0, stream>>>(x, wl, wc, out);
  }
}

// Round 3
// 487.801 us; speedup vs baseline: 1.0554x; 1.0431x over previous
//
#include <hip/hip_runtime.h>
#include <hip/hip_bf16.h>

// HopfieldLayer: out = softmax(x @ Wl^T * beta) @ Wc^T
//   x  [16384, 768] f32, Wl [4096, 768] f32, Wc [768, 4096] f32 -> out [16384, 768] f32
// bf16 MFMA. R3: BK=32 double-buffered K-loop with prefetch issued BEFORE compute
// (barrier's vmcnt(0) drain overlaps the compute window), constant-offset LDS
// halves (exact alias analysis), grid transposed so dispatch-consecutive blocks
// are different M-bands at the same n0 -> per-XCD L2 A-band residency.

#define NTOK   16384
#define DIM    768
#define NPROT  4096
#define BETA_F 0.03608439182428583f

typedef __bf16 bf16_t;
typedef __bf16 bf16x8 __attribute__((ext_vector_type(8)));
typedef float  floatx4 __attribute__((ext_vector_type(4)));

// ---------------------------------------------------------------- async 16B copy
__device__ __forceinline__ void async_copy16(const bf16_t* g, void* l) {
  __builtin_amdgcn_global_load_lds(
      (__attribute__((address_space(1))) const void*)g,
      (__attribute__((address_space(3))) void*)l, 16, 0, 0);
}

// ---------------------------------------------------------------- f32 -> bf16 (all 3 inputs)
__global__ __launch_bounds__(256) void cvt_all(
    const float* __restrict__ x, const float* __restrict__ wl,
    const float* __restrict__ wc, bf16_t* __restrict__ xb,
    bf16_t* __restrict__ wlb, bf16_t* __restrict__ wcb,
    int nx8, int nw8, int nc8) {
  int i = blockIdx.x * 256 + threadIdx.x;
  const float* in; bf16_t* out; int k;
  if (i < nx8)            { in = x;  out = xb;  k = i; }
  else if (i < nx8 + nw8) { in = wl; out = wlb; k = i - nx8; }
  else if (i < nx8 + nw8 + nc8) { in = wc; out = wcb; k = i - nx8 - nw8; }
  else return;
  const float4* in4 = (const float4*)in;
  float4 a = in4[2 * k], b = in4[2 * k + 1];
  bf16x8 o;
  o[0] = (bf16_t)a.x; o[1] = (bf16_t)a.y; o[2] = (bf16_t)a.z; o[3] = (bf16_t)a.w;
  o[4] = (bf16_t)b.x; o[5] = (bf16_t)b.y; o[6] = (bf16_t)b.z; o[7] = (bf16_t)b.w;
  ((bf16x8*)out)[k] = o;
}

// ---------------------------------------------------------------- gemm C = A * B^T
// A: M x K row-major bf16, B: N x K row-major bf16. 128x128 tile, 4 waves 2x2,
// each 64x64 (4x4 of 16x16x32 MFMA). BK=32, double-buffered: LDS halves at
// byte 0 and 16384 (each: A frags 8KB + B frags 8KB, fragment-ordered so
// global_load_lds uniform-base+lane*16 and ds_read_b128 are conflict-free).
// Grid: (M/128, N/128); blockIdx.x = M-band (fast-varying in dispatch order).
// EPI 0: P = exp(beta*acc) bf16, scattered stores + shuffle rowsum + atomics.
// EPI 1: O(f32) = acc / rowsum[row].
template <int EPI>
__global__ __launch_bounds__(256, 4)
void gemm_bt(const bf16_t* __restrict__ A, const bf16_t* __restrict__ B,
             void* __restrict__ Cv, float* __restrict__ rowsum,
             const int K, const int N) {
  __shared__ alignas(16) char lds[32768];

  const int tid = threadIdx.x;
  const int l   = tid & 63;
  const int w   = tid >> 6;
  const int wr  = w >> 1;        // wave row (0..1)
  const int wc  = w & 1;         // wave col (0..1)
  const int lr  = l & 15;        // row within 16x16 fragment
  const int lk  = (l >> 4) << 3; // k offset within fragment (0,8,16,24)
  const int m0  = blockIdx.x * 128;   // transposed grid: x = M-band
  const int n0  = blockIdx.y * 128;

  // staging bases: thread (w,l), chunk j -> fragment j*4+w (16 rows x 32 K = 1KB)
  int abase[2], bbase[2];
#pragma unroll
  for (int j = 0; j < 2; ++j) {
    const int frag = j * 4 + w;
    abase[j] = (m0 + frag * 16 + lr) * K + lk;
    bbase[j] = (n0 + frag * 16 + lr) * K + lk;
  }

  auto stage = [&](char* buf, int k0) {
    bf16x8* Af = (bf16x8*)buf;
    bf16x8* Bf = (bf16x8*)(buf + 8192);
#pragma unroll
    for (int j = 0; j < 2; ++j) {
      const int frag = j * 4 + w;
      async_copy16(A + abase[j] + k0, Af + frag * 64);
      async_copy16(B + bbase[j] + k0, Bf + frag * 64);
    }
  };

  const floatx4 z = {0.f, 0.f, 0.f, 0.f};
  floatx4 acc[4][4];
#pragma unroll
  for (int mt = 0; mt < 4; ++mt)
#pragma unroll
    for (int nt = 0; nt < 4; ++nt) acc[mt][nt] = z;

  auto compute = [&](const char* buf) {
    const bf16x8* Af = (const bf16x8*)buf;
    const bf16x8* Bf = (const bf16x8*)(buf + 8192);
    bf16x8 af[4], bg[4];
#pragma unroll
    for (int mt = 0; mt < 4; ++mt) af[mt] = Af[(wr * 4 + mt) * 64 + l];
#pragma unroll
    for (int nt = 0; nt < 4; ++nt) bg[nt] = Bf[(wc * 4 + nt) * 64 + l];
#pragma unroll
    for (int mt = 0; mt < 4; ++mt)
#pragma unroll
      for (int nt = 0; nt < 4; ++nt)
        acc[mt][nt] = __builtin_amdgcn_mfma_f32_16x16x32_bf16(af[mt], bg[nt],
                                                              acc[mt][nt], 0, 0, 0);
  };

  const int iters = K >> 5;  // 24 (K=768) or 128 (K=4096) -- both even
  stage(lds, 0);
  __syncthreads();
  for (int it = 0; it < iters; it += 2) {
    stage(lds + 16384, (it + 1) << 5);   // prefetch odd tile, flies during compute
    compute(lds);
    __syncthreads();                      // drains vmcnt(0): odd tile ready
    if (it + 2 < iters) stage(lds, (it + 2) << 5);
    compute(lds + 16384);
    __syncthreads();
  }

  // C/D layout (verified m89): col = lane&15, row = (lane>>4)*4 + i
  const int rowb = m0 + wr * 64;
  const int colb = n0 + wc * 64;
  if (EPI == 0) {
    bf16_t* P = (bf16_t*)Cv;
#pragma unroll
    for (int mt = 0; mt < 4; ++mt) {
      float rsum[4] = {0.f, 0.f, 0.f, 0.f};
#pragma unroll
      for (int nt = 0; nt < 4; ++nt) {
#pragma unroll
        for (int i = 0; i < 4; ++i) {
          const float e = __expf(acc[mt][nt][i] * BETA_F);
          const int row = rowb + mt * 16 + (l >> 4) * 4 + i;
          const int col = colb + nt * 16 + lr;
          P[row * N + col] = (bf16_t)e;
          rsum[i] += e;
        }
      }
#pragma unroll
      for (int i = 0; i < 4; ++i) {  // reduce across the 16 col-lanes
        float s = rsum[i];
        s += __shfl_xor(s, 1);
        s += __shfl_xor(s, 2);
        s += __shfl_xor(s, 4);
        s += __shfl_xor(s, 8);
        if (lr == 0)
          atomicAdd(&rowsum[rowb + mt * 16 + (l >> 4) * 4 + i], s);
      }
    }
  } else {
    float* O = (float*)Cv;
#pragma unroll
    for (int mt = 0; mt < 4; ++mt) {
#pragma unroll
      for (int i = 0; i < 4; ++i) {
        const int row = rowb + mt * 16 + (l >> 4) * 4 + i;
        const float inv = 1.0f / rowsum[row];
#pragma unroll
        for (int nt = 0; nt < 4; ++nt)
          O[row * N + colb + nt * 16 + lr] = acc[mt][nt][i] * inv;
      }
    }
  }
}

// ---------------------------------------------------------------- fallback (no ws)
__global__ __launch_bounds__(256) void hopfield_fallback(
    const float* __restrict__ x, const float* __restrict__ wl,
    const float* __restrict__ wc, float* __restrict__ out) {
  __shared__ float  xs[8 * 768];
  __shared__ bf16_t ps[8 * 4096];
  __shared__ float  rs[8];
  const int tid = threadIdx.x;
  const int r0  = blockIdx.x * 8;
  if (tid < 8) rs[tid] = 0.f;
  for (int i = tid; i < 8 * 768; i += 256)
    xs[i] = x[(r0 + (i / 768)) * 768 + (i % 768)];
  __syncthreads();

  float lsum[8] = {0, 0, 0, 0, 0, 0, 0, 0};
  for (int p = tid; p < 4096; p += 256) {
    float s[8] = {0, 0, 0, 0, 0, 0, 0, 0};
    for (int d = 0; d < 768; ++d) {
      const float wv = wl[p * 768 + d];
#pragma unroll
      for (int r = 0; r < 8; ++r) s[r] += xs[r * 768 + d] * wv;
    }
#pragma unroll
    for (int r = 0; r < 8; ++r) {
      const float e = __expf(s[r] * BETA_F);
      ps[r * 4096 + p] = (bf16_t)e;
      lsum[r] += e;
    }
  }
#pragma unroll
  for (int r = 0; r < 8; ++r) atomicAdd(&rs[r], lsum[r]);
  __syncthreads();

  for (int d = tid; d < 768; d += 256) {
    float o[8] = {0, 0, 0, 0, 0, 0, 0, 0};
    for (int p = 0; p < 4096; ++p) {
      const float wv = wc[d * 4096 + p];
#pragma unroll
      for (int r = 0; r < 8; ++r) o[r] += (float)ps[r * 4096 + p] * wv;
    }
#pragma unroll
    for (int r = 0; r < 8; ++r) out[(r0 + r) * 768 + d] = o[r] / rs[r];
  }
}

// ---------------------------------------------------------------- launcher
extern "C" void kernel_launch(void* const* d_in, const int* in_sizes, int n_in,
                              void* d_out, int out_size, void* d_ws, size_t ws_size,
                              hipStream_t stream) {
  (void)in_sizes; (void)n_in; (void)out_size;
  const float* x  = (const float*)d_in[0];
  const float* wl = (const float*)d_in[1];
  const float* wc = (const float*)d_in[2];
  float* out = (float*)d_out;

  const size_t xb_e = (size_t)NTOK * DIM;    // 12.58M
  const size_t wl_e = (size_t)NPROT * DIM;   // 3.15M
  const size_t wc_e = (size_t)DIM * NPROT;   // 3.15M
  const size_t P_e  = (size_t)NTOK * NPROT;  // 67.1M
  const size_t need = (xb_e + wl_e + wc_e + P_e) * 2 + (size_t)NTOK * 4;

  if (ws_size >= need) {
    char* ws = (char*)d_ws;
    bf16_t* xb  = (bf16_t*)ws;  ws += xb_e * 2;
    bf16_t* wlb = (bf16_t*)ws;  ws += wl_e * 2;
    bf16_t* wcb = (bf16_t*)ws;  ws += wc_e * 2;
    bf16_t* P   = (bf16_t*)ws;  ws += P_e * 2;
    float* rowsum = (float*)ws;

    hipMemsetAsync(rowsum, 0, NTOK * sizeof(float), stream);
    const int nx8 = (int)(xb_e / 8), nw8 = (int)(wl_e / 8), nc8 = (int)(wc_e / 8);
    cvt_all<<<(nx8 + nw8 + nc8 + 255) / 256, 256, 0, stream>>>(
        x, wl, wc, xb, wlb, wcb, nx8, nw8, nc8);
    // scores+exp+rowsum: M=16384, N=4096, K=768  (grid: x = M-bands)
    gemm_bt<0><<<dim3(NTOK / 128, NPROT / 128), 256, 0, stream>>>(
        xb, wlb, (void*)P, rowsum, DIM, NPROT);
    // content+normalize: M=16384, N=768, K=4096
    gemm_bt<1><<<dim3(NTOK / 128, DIM / 128), 256, 0, stream>>>(
        P, wcb, (void*)out, rowsum, NPROT, DIM);
  } else {
    hopfield_fallback<<<NTOK / 8, 256, 0, stream>>>(x, wl, wc, out);
  }
}